// Round 9
// baseline (384.149 us; speedup 1.0000x reference)
//
#include <hip/hip_runtime.h>
#include <hip/hip_bf16.h>

#define BATCH 2
#define SEQ   2048
#define NH    16
#define NKV   4
#define HD    128
#define KDIM  2048
#define MROWS 4096
#define NQKV  3072

typedef __attribute__((ext_vector_type(8))) short  s16x8;
typedef __attribute__((ext_vector_type(4))) short  s16x4;
typedef __attribute__((ext_vector_type(4))) float  f32x4;
typedef __attribute__((ext_vector_type(8))) __bf16 b16x8;

// barrier that drains LDS ops only -- leaves global prefetch loads in flight
#define BARRIER_LDS() do { \
    asm volatile("s_waitcnt lgkmcnt(0)" ::: "memory"); \
    __builtin_amdgcn_s_barrier(); \
  } while (0)

__device__ __forceinline__ unsigned short f2bf(float f) {
  __hip_bfloat16 h = __float2bfloat16(f);
  return *reinterpret_cast<unsigned short*>(&h);
}
__device__ __forceinline__ float bf2f(unsigned short h) {
  union { unsigned int u; float f; } x; x.u = ((unsigned int)h) << 16;
  return x.f;
}

__device__ __forceinline__ f32x4 MFMA16(s16x8 a, s16x8 b, f32x4 c) {
  return __builtin_amdgcn_mfma_f32_16x16x32_bf16(
      __builtin_bit_cast(b16x8, a), __builtin_bit_cast(b16x8, b), c, 0, 0, 0);
}

__device__ __forceinline__ void gload_lds16(const void* g, void* lds) {
  __builtin_amdgcn_global_load_lds(
      (const __attribute__((address_space(1))) void*)g,
      (__attribute__((address_space(3))) void*)lds, 16, 0, 0);
}

// ---------------- W (KxN f32) -> WT (NxK bf16) ----------------
__global__ __launch_bounds__(256) void transpose_convert(
    const float* __restrict__ W, unsigned short* __restrict__ WT, int Kd, int Nd) {
  __shared__ float tile[32][33];
  int n0 = blockIdx.x * 32, k0 = blockIdx.y * 32;
  int tx = threadIdx.x & 31, ty = threadIdx.x >> 5;
#pragma unroll
  for (int i = 0; i < 4; ++i)
    tile[ty + i * 8][tx] = W[(size_t)(k0 + ty + i * 8) * Nd + n0 + tx];
  __syncthreads();
#pragma unroll
  for (int i = 0; i < 4; ++i)
    WT[(size_t)(n0 + ty + i * 8) * Kd + k0 + tx] = f2bf(tile[tx][ty + i * 8]);
}

// ---------------- f32 -> bf16 bulk convert ----------------
__global__ __launch_bounds__(256) void conv_bf16(
    const float* __restrict__ X, unsigned short* __restrict__ Y) {
  int i = blockIdx.x * 256 + threadIdx.x;
  const float4 a = ((const float4*)X)[2 * i];
  const float4 b = ((const float4*)X)[2 * i + 1];
  s16x8 o;
  o[0] = (short)f2bf(a.x); o[1] = (short)f2bf(a.y);
  o[2] = (short)f2bf(a.z); o[3] = (short)f2bf(a.w);
  o[4] = (short)f2bf(b.x); o[5] = (short)f2bf(b.y);
  o[6] = (short)f2bf(b.z); o[7] = (short)f2bf(b.w);
  ((s16x8*)Y)[i] = o;
}

// ---------------- RoPE cos/sin table ----------------
__global__ __launch_bounds__(256) void rope_table_kernel(float* __restrict__ tbl) {
  int i = blockIdx.x * 256 + threadIdx.x;
  int s = i >> 6, j = i & 63;
  float inv = powf(10000.0f, -(float)(2 * j) * (1.0f / 128.0f));
  float f = (float)s * inv;
  tbl[2 * i]     = cosf(f);
  tbl[2 * i + 1] = sinf(f);
}

// ---------------- QKV GEMM: BK=64, source-swizzled LDS, XCD grid ----------------
__global__ __launch_bounds__(256) void gemm_qkv(
    const unsigned short* __restrict__ A, const unsigned short* __restrict__ BT,
    unsigned short* __restrict__ Qo, unsigned short* __restrict__ Ko,
    unsigned short* __restrict__ Vo) {
  __shared__ __align__(16) unsigned short la[128][64];
  __shared__ __align__(16) unsigned short lb[128][64];
  int tid = threadIdx.x, lane = tid & 63, w = tid >> 6;
  int lin = blockIdx.x;
  int swz = (lin & 7) * 96 + (lin >> 3);
  int bx = swz % 24, by = swz / 24;
  int m0 = by * 128, n0 = bx * 128;
  int wr = (w >> 1) * 64, wc = (w & 1) * 64;
  int fr = lane & 15, g = lane >> 4, rg = g * 4;
  int srow = tid >> 3, sc_ = ((tid & 7) ^ (srow & 7)) * 8;  // swizzled source chunk
  f32x4 acc[4][4] = {};
  for (int kt = 0; kt < KDIM; kt += 64) {
    __syncthreads();
#pragma unroll
    for (int i = 0; i < 4; ++i) {
      int idx = tid + i * 256;
      int row = srow + i * 32;
      gload_lds16(A + (size_t)(m0 + row) * KDIM + kt + sc_,
                  (char*)la + (size_t)idx * 16);
      gload_lds16(BT + (size_t)(n0 + row) * KDIM + kt + sc_,
                  (char*)lb + (size_t)idx * 16);
    }
    __syncthreads();
#pragma unroll
    for (int kk = 0; kk < 2; ++kk) {
      s16x8 af[4], bf[4];
#pragma unroll
      for (int mi = 0; mi < 4; ++mi) {
        int R = wr + mi * 16 + fr;
        af[mi] = *(const s16x8*)((const unsigned short*)la + R * 64 + ((((kk << 2) | g)) ^ (R & 7)) * 8);
      }
#pragma unroll
      for (int ni = 0; ni < 4; ++ni) {
        int R = wc + ni * 16 + fr;
        bf[ni] = *(const s16x8*)((const unsigned short*)lb + R * 64 + ((((kk << 2) | g)) ^ (R & 7)) * 8);
      }
#pragma unroll
      for (int mi = 0; mi < 4; ++mi)
#pragma unroll
        for (int ni = 0; ni < 4; ++ni) acc[mi][ni] = MFMA16(af[mi], bf[ni], acc[mi][ni]);
    }
  }
  int rbase = m0 + wr + rg;
#pragma unroll
  for (int ni = 0; ni < 4; ++ni) {
    int gn = n0 + wc + ni * 16 + fr;
    if (gn < 2048) {
      int hh = gn >> 7, d = gn & 127;
#pragma unroll
      for (int mi = 0; mi < 4; ++mi)
#pragma unroll
        for (int r = 0; r < 4; ++r) {
          int grow = rbase + mi * 16 + r;
          int bb = grow >> 11, ss = grow & 2047;
          Qo[((size_t)(bb * NH + hh) * SEQ + ss) * HD + d] = f2bf(acc[mi][ni][r]);
        }
    } else if (gn < 2560) {
      int c = gn - 2048, kvh = c >> 7, d = c & 127;
#pragma unroll
      for (int mi = 0; mi < 4; ++mi)
#pragma unroll
        for (int r = 0; r < 4; ++r) {
          int grow = rbase + mi * 16 + r;
          int bb = grow >> 11, ss = grow & 2047;
          Ko[((size_t)(bb * NKV + kvh) * SEQ + ss) * HD + d] = f2bf(acc[mi][ni][r]);
        }
    } else {
      int c = gn - 2560, kvh = c >> 7, d = c & 127;
#pragma unroll
      for (int mi = 0; mi < 4; ++mi) {
        int grow0 = rbase + mi * 16;
        int bb = grow0 >> 11, ss = grow0 & 2047;
        s16x4 pk;
#pragma unroll
        for (int r = 0; r < 4; ++r) pk[r] = (short)f2bf(acc[mi][ni][r]);
        *(s16x4*)(Vo + ((size_t)(bb * NKV + kvh) * HD + d) * SEQ + ss) = pk;
      }
    }
  }
}

// ---------------- O-proj GEMM: BK=64, source-swizzled LDS, XCD grid ----------------
__global__ __launch_bounds__(256) void gemm_out(
    const unsigned short* __restrict__ A, const unsigned short* __restrict__ BT,
    float* __restrict__ C) {
  __shared__ __align__(16) unsigned short la[128][64];
  __shared__ __align__(16) unsigned short lb[128][64];
  int tid = threadIdx.x, lane = tid & 63, w = tid >> 6;
  int lin = blockIdx.x;
  int swz = (lin & 7) * 64 + (lin >> 3);
  int bx = swz % 16, by = swz / 16;
  int m0 = by * 128, n0 = bx * 128;
  int wr = (w >> 1) * 64, wc = (w & 1) * 64;
  int fr = lane & 15, g = lane >> 4, rg = g * 4;
  int srow = tid >> 3, sc_ = ((tid & 7) ^ (srow & 7)) * 8;
  f32x4 acc[4][4] = {};
  for (int kt = 0; kt < KDIM; kt += 64) {
    __syncthreads();
#pragma unroll
    for (int i = 0; i < 4; ++i) {
      int idx = tid + i * 256;
      int row = srow + i * 32;
      gload_lds16(A + (size_t)(m0 + row) * KDIM + kt + sc_,
                  (char*)la + (size_t)idx * 16);
      gload_lds16(BT + (size_t)(n0 + row) * KDIM + kt + sc_,
                  (char*)lb + (size_t)idx * 16);
    }
    __syncthreads();
#pragma unroll
    for (int kk = 0; kk < 2; ++kk) {
      s16x8 af[4], bf[4];
#pragma unroll
      for (int mi = 0; mi < 4; ++mi) {
        int R = wr + mi * 16 + fr;
        af[mi] = *(const s16x8*)((const unsigned short*)la + R * 64 + ((((kk << 2) | g)) ^ (R & 7)) * 8);
      }
#pragma unroll
      for (int ni = 0; ni < 4; ++ni) {
        int R = wc + ni * 16 + fr;
        bf[ni] = *(const s16x8*)((const unsigned short*)lb + R * 64 + ((((kk << 2) | g)) ^ (R & 7)) * 8);
      }
#pragma unroll
      for (int mi = 0; mi < 4; ++mi)
#pragma unroll
        for (int ni = 0; ni < 4; ++ni) acc[mi][ni] = MFMA16(af[mi], bf[ni], acc[mi][ni]);
    }
  }
  int rbase = m0 + wr + rg;
#pragma unroll
  for (int ni = 0; ni < 4; ++ni) {
    int gn = n0 + wc + ni * 16 + fr;
#pragma unroll
    for (int mi = 0; mi < 4; ++mi)
#pragma unroll
      for (int r = 0; r < 4; ++r)
        C[(size_t)(rbase + mi * 16 + r) * 2048 + gn] = acc[mi][ni][r];
  }
}

// ---------------- RoPE on [rows][128] contiguous layout ----------------
__global__ __launch_bounds__(256) void rope2(
    unsigned short* __restrict__ X, const float* __restrict__ tbl) {
  __shared__ __align__(16) unsigned short xs[32][136];
  int tid = threadIdx.x;
  size_t r0 = (size_t)blockIdx.x * 32;
#pragma unroll
  for (int i = 0; i < 2; ++i) {
    int idx = tid + i * 256;
    int pr = idx >> 4, seg = idx & 15;
    *(s16x8*)(&xs[pr][seg * 8]) = *(const s16x8*)(X + (r0 + pr) * 128 + seg * 8);
  }
  __syncthreads();
  int pr = tid >> 3, jb = (tid & 7) * 8;
  size_t row = r0 + pr;
  int s = (int)(row & (SEQ - 1));
  s16x8 o0, o1;
#pragma unroll
  for (int j0 = 0; j0 < 8; ++j0) {
    int j = jb + j0;
    float c  = tbl[(s * 64 + j) * 2];
    float sn = tbl[(s * 64 + j) * 2 + 1];
    float xj   = bf2f(xs[pr][j]);
    float xj64 = bf2f(xs[pr][j + 64]);
    float x2j  = bf2f(xs[pr][2 * j]);
    float x2j1 = bf2f(xs[pr][2 * j + 1]);
    o0[j0] = (short)f2bf(xj * c - x2j1 * sn);
    o1[j0] = (short)f2bf(xj64 * c + x2j * sn);
  }
  unsigned short* xp = X + row * 128;
  *(s16x8*)(xp + jb)      = o0;
  *(s16x8*)(xp + 64 + jb) = o1;
}

// ---------------- Flash attention v9: V direct from L2, 1 barrier/tile, 3 blk/CU ----------------
// grid 512 x 512thr: XCD (l&7) owns one (b,kvh); slot: hloc(2b) + p(4b).
// Waves 0-3 -> qt=31-p; waves 4-7 -> qt=p. K double-buffered in LDS (44KB tot).
__global__ __launch_bounds__(512, 2) void attn_fwd(
    const unsigned short* __restrict__ Q, const unsigned short* __restrict__ K,
    const unsigned short* __restrict__ VT, const float* __restrict__ mask,
    unsigned short* __restrict__ O) {
  __shared__ __align__(16) unsigned short kt_[2][64][136];
  __shared__ __align__(16) unsigned short pt_[8][16][36];

  int tid = threadIdx.x, lane = tid & 63, w = tid >> 6;
  int l = blockIdx.x;
  int grp = l & 7, slot = l >> 3;
  int hloc = slot & 3, p = slot >> 2;            // p 0..15
  int b = grp >> 2, kvh = grp & 3, h = kvh * 4 + hloc;
  int half = w >> 2, wsub = w & 3;
  int qt = half ? p : 31 - p;
  int qw = qt * 64 + wsub * 16;                  // wave's 16 q-rows
  int fr = lane & 15, g = lane >> 4, kg = g * 8, rg = g * 4;

  const unsigned short* Qb = Q + (size_t)(b * NH + h) * SEQ * HD;
  const unsigned short* Kb = K + (size_t)(b * NKV + kvh) * SEQ * HD;
  const unsigned short* Vb = VT + (size_t)(b * NKV + kvh) * HD * SEQ;
  const float* mb = mask + (size_t)b * SEQ;

  // K staging geometry (512 threads, 2 chunks each)
  int krow = tid >> 4, kpos = (tid & 15) * 8;    // K rows krow, krow+32

  const float sc2 = 0.12751744584812722f;        // 1/sqrt(128) * log2(e)
  const float L2E = 1.44269504088896f;
  int bS = b * SEQ;
  int ntiles = 32 - p;                           // qtA + 1

  s16x8 aq[4];
#pragma unroll
  for (int dc = 0; dc < 4; ++dc)
    aq[dc] = *(const s16x8*)(Qb + (size_t)(qw + fr) * HD + dc * 32 + kg);

  f32x4 oacc[8] = {};
  float m_r = -3e38f, l_r = 0.f;

  s16x8 kreg[2];
  // prologue: K(0) -> kt_[0]
  kreg[0] = *(const s16x8*)(Kb + (size_t)krow * HD + kpos);
  kreg[1] = *(const s16x8*)(Kb + (size_t)(krow + 32) * HD + kpos);
  *(s16x8*)(&kt_[0][krow][kpos])      = kreg[0];
  *(s16x8*)(&kt_[0][krow + 32][kpos]) = kreg[1];
  BARRIER_LDS();

  int cur = 0;
  for (int t = 0; t < ntiles; ++t) {
    int kv0 = t * 64;
    bool notlast = (t + 1 < ntiles);
    bool active = (kv0 <= qw + 15);              // wave-uniform
    bool diag   = (kv0 + 63 > qw);

    // issue K(t+1) -> regs (stays in flight across the barrier)
    if (notlast) {
      kreg[0] = *(const s16x8*)(Kb + (size_t)(kv0 + 64 + krow) * HD + kpos);
      kreg[1] = *(const s16x8*)(Kb + (size_t)(kv0 + 96 + krow) * HD + kpos);
    }

    f32x4 sf[4];
    if (active) {
      // QK^T: S^T element (kv = kv0+mk*16+rg+r, q = qw+fr)
      __builtin_amdgcn_s_setprio(1);
#pragma unroll
      for (int mk = 0; mk < 4; ++mk) {
        s16x8 ak[4];
#pragma unroll
        for (int dc = 0; dc < 4; ++dc)
          ak[dc] = *(const s16x8*)(&kt_[cur][mk * 16 + fr][dc * 32 + kg]);
        sf[mk] = f32x4{0.f, 0.f, 0.f, 0.f};
#pragma unroll
        for (int dc = 0; dc < 4; ++dc)
          sf[mk] = MFMA16(ak[dc], aq[dc], sf[mk]);
      }
      __builtin_amdgcn_s_setprio(0);

      // scale + mask (log2 domain); causal select only on diagonal tile
#pragma unroll
      for (int mk = 0; mk < 4; ++mk) {
        float4 mv = *(const float4*)(mb + kv0 + mk * 16 + rg);
        float mvr[4] = {mv.x * L2E, mv.y * L2E, mv.z * L2E, mv.w * L2E};
        if (diag) {
#pragma unroll
          for (int r = 0; r < 4; ++r) {
            int kv = kv0 + mk * 16 + rg + r;
            float v = sf[mk][r] * sc2 + mvr[r];
            sf[mk][r] = (kv <= qw + fr) ? v : -3e38f;
          }
        } else {
#pragma unroll
          for (int r = 0; r < 4; ++r)
            sf[mk][r] = sf[mk][r] * sc2 + mvr[r];
        }
      }

      // online softmax (exp2 domain); tree max
      float pm01a = fmaxf(sf[0][0], sf[0][1]), pm01b = fmaxf(sf[0][2], sf[0][3]);
      float pm11a = fmaxf(sf[1][0], sf[1][1]), pm11b = fmaxf(sf[1][2], sf[1][3]);
      float pm21a = fmaxf(sf[2][0], sf[2][1]), pm21b = fmaxf(sf[2][2], sf[2][3]);
      float pm31a = fmaxf(sf[3][0], sf[3][1]), pm31b = fmaxf(sf[3][2], sf[3][3]);
      float pm0 = fmaxf(pm01a, pm01b), pm1 = fmaxf(pm11a, pm11b);
      float pm2 = fmaxf(pm21a, pm21b), pm3 = fmaxf(pm31a, pm31b);
      float pm = fmaxf(fmaxf(pm0, pm1), fmaxf(pm2, pm3));
      pm = fmaxf(pm, __shfl_xor(pm, 16, 64));
      pm = fmaxf(pm, __shfl_xor(pm, 32, 64));
      if (!__all(pm - m_r <= 8.0f)) {
        float mo = m_r;
        float mn = fmaxf(mo, pm);
        float al = exp2f(mo - mn);
        m_r = mn;
        l_r *= al;
#pragma unroll
        for (int r = 0; r < 4; ++r) {
          float ar = __shfl(al, rg + r, 16);
#pragma unroll
          for (int od = 0; od < 8; ++od) oacc[od][r] *= ar;
        }
      }
      float rs = 0.f;
#pragma unroll
      for (int mk = 0; mk < 4; ++mk)
#pragma unroll
        for (int r = 0; r < 4; ++r) {
          float ppv = exp2f(sf[mk][r] - m_r);
          sf[mk][r] = ppv;
          rs += ppv;
        }
      rs += __shfl_xor(rs, 16, 64);
      rs += __shfl_xor(rs, 32, 64);
      l_r += rs;
    }

    // write K(t+1) into the other buffer (pre-barrier; reads are post-barrier)
    if (notlast) {
      *(s16x8*)(&kt_[cur ^ 1][krow][kpos])      = kreg[0];
      *(s16x8*)(&kt_[cur ^ 1][krow + 32][kpos]) = kreg[1];
    }

    if (active) {
      // PV: P -> pt_ (per-wave, same-wave read); V^T direct from global (L1/L2)
#pragma unroll
      for (int kk = 0; kk < 2; ++kk) {
#pragma unroll
        for (int mh = 0; mh < 2; ++mh) {
          int mk = kk * 2 + mh;
          s16x4 pk;
#pragma unroll
          for (int r = 0; r < 4; ++r) pk[r] = (short)f2bf(sf[mk][r]);
          *(s16x4*)(&pt_[w][fr][mh * 16 + rg]) = pk;
        }
        s16x8 ap = *(const s16x8*)(&pt_[w][fr][kg]);
        __builtin_amdgcn_s_setprio(1);
#pragma unroll
        for (int od = 0; od < 8; ++od) {
          s16x8 bv = *(const s16x8*)(Vb + (size_t)(od * 16 + fr) * SEQ + kv0 + kk * 32 + kg);
          oacc[od] = MFMA16(ap, bv, oacc[od]);
        }
        __builtin_amdgcn_s_setprio(0);
      }
    }
    BARRIER_LDS();  // single barrier: kt_[cur^1]=K(t+1) visible; kt_[cur] reads done
    cur ^= 1;
  }

  // epilogue: O element (q = qw+rg+r, d = od*16+fr)
  float iv = 1.0f / l_r;
  float ivr[4];
#pragma unroll
  for (int r = 0; r < 4; ++r) ivr[r] = __shfl(iv, rg + r, 16);
#pragma unroll
  for (int r = 0; r < 4; ++r) {
    unsigned short* op = O + (size_t)(bS + qw + rg + r) * 2048 + h * 128 + fr;
#pragma unroll
    for (int od = 0; od < 8; ++od)
      op[od * 16] = f2bf(oacc[od][r] * ivr[r]);
  }
}

extern "C" void kernel_launch(void* const* d_in, const int* in_sizes, int n_in,
                              void* d_out, int out_size, void* d_ws, size_t ws_size,
                              hipStream_t stream) {
  const float* hidden = (const float*)d_in[0];
  const float* mask   = (const float*)d_in[1];
  const float* Wq     = (const float*)d_in[2];
  const float* Wk     = (const float*)d_in[3];
  const float* Wv     = (const float*)d_in[4];
  const float* Wo     = (const float*)d_in[5];
  float* out = (float*)d_out;

  char* ws = (char*)d_ws;
  unsigned short* BT  = (unsigned short*)(ws);                 // 3072x2048 bf16
  unsigned short* WoT = (unsigned short*)(ws + 12582912);      // 2048x2048 bf16
  unsigned short* Qb  = (unsigned short*)(ws + 20971520);      // [B][NH][S][HD]
  unsigned short* Kb  = (unsigned short*)(ws + 37748736);      // [B][NKV][S][HD]
  unsigned short* VT  = (unsigned short*)(ws + 41943040);      // [B][NKV][HD][S]
  unsigned short* AO  = (unsigned short*)(ws + 46137344);      // [MROWS][2048] bf16
  float*          tbl = (float*)(ws + 62914560);               // [S][64][2] f32
  unsigned short* Ab  = AO;  // hidden as bf16; dead before attn writes AO

  conv_bf16<<<MROWS * KDIM / (256 * 8), 256, 0, stream>>>(hidden, Ab);
  transpose_convert<<<dim3(64, 64), 256, 0, stream>>>(Wq, BT, KDIM, 2048);
  transpose_convert<<<dim3(16, 64), 256, 0, stream>>>(Wk, BT + (size_t)2048 * KDIM, KDIM, 512);
  transpose_convert<<<dim3(16, 64), 256, 0, stream>>>(Wv, BT + (size_t)2560 * KDIM, KDIM, 512);
  transpose_convert<<<dim3(64, 64), 256, 0, stream>>>(Wo, WoT, KDIM, 2048);
  rope_table_kernel<<<512, 256, 0, stream>>>(tbl);

  gemm_qkv<<<dim3(768), 256, 0, stream>>>(Ab, BT, Qb, Kb, VT);
  rope2<<<(BATCH * NH * SEQ) / 32, 256, 0, stream>>>(Qb, tbl);
  rope2<<<(BATCH * NKV * SEQ) / 32, 256, 0, stream>>>(Kb, tbl);
  attn_fwd<<<dim3(512), 512, 0, stream>>>(Qb, Kb, VT, mask, AO);
  gemm_out<<<dim3(512), 256, 0, stream>>>(AO, WoT, out);
}

// Round 10
// 378.492 us; speedup vs baseline: 1.0149x; 1.0149x over previous
//
#include <hip/hip_runtime.h>
#include <hip/hip_bf16.h>

#define BATCH 2
#define SEQ   2048
#define NH    16
#define NKV   4
#define HD    128
#define KDIM  2048
#define MROWS 4096
#define NQKV  3072

typedef __attribute__((ext_vector_type(8))) short  s16x8;
typedef __attribute__((ext_vector_type(4))) short  s16x4;
typedef __attribute__((ext_vector_type(4))) float  f32x4;
typedef __attribute__((ext_vector_type(8))) __bf16 b16x8;

// barrier that drains LDS ops only -- leaves global prefetch loads in flight
#define BARRIER_LDS() do { \
    asm volatile("s_waitcnt lgkmcnt(0)" ::: "memory"); \
    __builtin_amdgcn_s_barrier(); \
  } while (0)

__device__ __forceinline__ unsigned short f2bf(float f) {
  __hip_bfloat16 h = __float2bfloat16(f);
  return *reinterpret_cast<unsigned short*>(&h);
}
__device__ __forceinline__ float bf2f(unsigned short h) {
  union { unsigned int u; float f; } x; x.u = ((unsigned int)h) << 16;
  return x.f;
}

__device__ __forceinline__ f32x4 MFMA16(s16x8 a, s16x8 b, f32x4 c) {
  return __builtin_amdgcn_mfma_f32_16x16x32_bf16(
      __builtin_bit_cast(b16x8, a), __builtin_bit_cast(b16x8, b), c, 0, 0, 0);
}

__device__ __forceinline__ void gload_lds16(const void* g, void* lds) {
  __builtin_amdgcn_global_load_lds(
      (const __attribute__((address_space(1))) void*)g,
      (__attribute__((address_space(3))) void*)lds, 16, 0, 0);
}

// ---------------- W (KxN f32) -> WT (NxK bf16) ----------------
__global__ __launch_bounds__(256) void transpose_convert(
    const float* __restrict__ W, unsigned short* __restrict__ WT, int Kd, int Nd) {
  __shared__ float tile[32][33];
  int n0 = blockIdx.x * 32, k0 = blockIdx.y * 32;
  int tx = threadIdx.x & 31, ty = threadIdx.x >> 5;
#pragma unroll
  for (int i = 0; i < 4; ++i)
    tile[ty + i * 8][tx] = W[(size_t)(k0 + ty + i * 8) * Nd + n0 + tx];
  __syncthreads();
#pragma unroll
  for (int i = 0; i < 4; ++i)
    WT[(size_t)(n0 + ty + i * 8) * Kd + k0 + tx] = f2bf(tile[tx][ty + i * 8]);
}

// ---------------- f32 -> bf16 bulk convert ----------------
__global__ __launch_bounds__(256) void conv_bf16(
    const float* __restrict__ X, unsigned short* __restrict__ Y) {
  int i = blockIdx.x * 256 + threadIdx.x;
  const float4 a = ((const float4*)X)[2 * i];
  const float4 b = ((const float4*)X)[2 * i + 1];
  s16x8 o;
  o[0] = (short)f2bf(a.x); o[1] = (short)f2bf(a.y);
  o[2] = (short)f2bf(a.z); o[3] = (short)f2bf(a.w);
  o[4] = (short)f2bf(b.x); o[5] = (short)f2bf(b.y);
  o[6] = (short)f2bf(b.z); o[7] = (short)f2bf(b.w);
  ((s16x8*)Y)[i] = o;
}

// ---------------- RoPE cos/sin table ----------------
__global__ __launch_bounds__(256) void rope_table_kernel(float* __restrict__ tbl) {
  int i = blockIdx.x * 256 + threadIdx.x;
  int s = i >> 6, j = i & 63;
  float inv = powf(10000.0f, -(float)(2 * j) * (1.0f / 128.0f));
  float f = (float)s * inv;
  tbl[2 * i]     = cosf(f);
  tbl[2 * i + 1] = sinf(f);
}

// ---------------- QKV GEMM: BK=64, source-swizzled LDS, XCD grid ----------------
__global__ __launch_bounds__(256) void gemm_qkv(
    const unsigned short* __restrict__ A, const unsigned short* __restrict__ BT,
    unsigned short* __restrict__ Qo, unsigned short* __restrict__ Ko,
    unsigned short* __restrict__ Vo) {
  __shared__ __align__(16) unsigned short la[128][64];
  __shared__ __align__(16) unsigned short lb[128][64];
  int tid = threadIdx.x, lane = tid & 63, w = tid >> 6;
  int lin = blockIdx.x;
  int swz = (lin & 7) * 96 + (lin >> 3);
  int bx = swz % 24, by = swz / 24;
  int m0 = by * 128, n0 = bx * 128;
  int wr = (w >> 1) * 64, wc = (w & 1) * 64;
  int fr = lane & 15, g = lane >> 4, rg = g * 4;
  int srow = tid >> 3, sc_ = ((tid & 7) ^ (srow & 7)) * 8;  // swizzled source chunk
  f32x4 acc[4][4] = {};
  for (int kt = 0; kt < KDIM; kt += 64) {
    __syncthreads();
#pragma unroll
    for (int i = 0; i < 4; ++i) {
      int idx = tid + i * 256;
      int row = srow + i * 32;
      gload_lds16(A + (size_t)(m0 + row) * KDIM + kt + sc_,
                  (char*)la + (size_t)idx * 16);
      gload_lds16(BT + (size_t)(n0 + row) * KDIM + kt + sc_,
                  (char*)lb + (size_t)idx * 16);
    }
    __syncthreads();
#pragma unroll
    for (int kk = 0; kk < 2; ++kk) {
      s16x8 af[4], bf[4];
#pragma unroll
      for (int mi = 0; mi < 4; ++mi) {
        int R = wr + mi * 16 + fr;
        af[mi] = *(const s16x8*)((const unsigned short*)la + R * 64 + ((((kk << 2) | g)) ^ (R & 7)) * 8);
      }
#pragma unroll
      for (int ni = 0; ni < 4; ++ni) {
        int R = wc + ni * 16 + fr;
        bf[ni] = *(const s16x8*)((const unsigned short*)lb + R * 64 + ((((kk << 2) | g)) ^ (R & 7)) * 8);
      }
#pragma unroll
      for (int mi = 0; mi < 4; ++mi)
#pragma unroll
        for (int ni = 0; ni < 4; ++ni) acc[mi][ni] = MFMA16(af[mi], bf[ni], acc[mi][ni]);
    }
  }
  int rbase = m0 + wr + rg;
#pragma unroll
  for (int ni = 0; ni < 4; ++ni) {
    int gn = n0 + wc + ni * 16 + fr;
    if (gn < 2048) {
      int hh = gn >> 7, d = gn & 127;
#pragma unroll
      for (int mi = 0; mi < 4; ++mi)
#pragma unroll
        for (int r = 0; r < 4; ++r) {
          int grow = rbase + mi * 16 + r;
          int bb = grow >> 11, ss = grow & 2047;
          Qo[((size_t)(bb * NH + hh) * SEQ + ss) * HD + d] = f2bf(acc[mi][ni][r]);
        }
    } else if (gn < 2560) {
      int c = gn - 2048, kvh = c >> 7, d = c & 127;
#pragma unroll
      for (int mi = 0; mi < 4; ++mi)
#pragma unroll
        for (int r = 0; r < 4; ++r) {
          int grow = rbase + mi * 16 + r;
          int bb = grow >> 11, ss = grow & 2047;
          Ko[((size_t)(bb * NKV + kvh) * SEQ + ss) * HD + d] = f2bf(acc[mi][ni][r]);
        }
    } else {
      int c = gn - 2560, kvh = c >> 7, d = c & 127;
#pragma unroll
      for (int mi = 0; mi < 4; ++mi) {
        int grow0 = rbase + mi * 16;
        int bb = grow0 >> 11, ss = grow0 & 2047;
        s16x4 pk;
#pragma unroll
        for (int r = 0; r < 4; ++r) pk[r] = (short)f2bf(acc[mi][ni][r]);
        *(s16x4*)(Vo + ((size_t)(bb * NKV + kvh) * HD + d) * SEQ + ss) = pk;
      }
    }
  }
}

// ---------------- O-proj GEMM: BK=64, source-swizzled LDS, XCD grid ----------------
__global__ __launch_bounds__(256) void gemm_out(
    const unsigned short* __restrict__ A, const unsigned short* __restrict__ BT,
    float* __restrict__ C) {
  __shared__ __align__(16) unsigned short la[128][64];
  __shared__ __align__(16) unsigned short lb[128][64];
  int tid = threadIdx.x, lane = tid & 63, w = tid >> 6;
  int lin = blockIdx.x;
  int swz = (lin & 7) * 64 + (lin >> 3);
  int bx = swz % 16, by = swz / 16;
  int m0 = by * 128, n0 = bx * 128;
  int wr = (w >> 1) * 64, wc = (w & 1) * 64;
  int fr = lane & 15, g = lane >> 4, rg = g * 4;
  int srow = tid >> 3, sc_ = ((tid & 7) ^ (srow & 7)) * 8;
  f32x4 acc[4][4] = {};
  for (int kt = 0; kt < KDIM; kt += 64) {
    __syncthreads();
#pragma unroll
    for (int i = 0; i < 4; ++i) {
      int idx = tid + i * 256;
      int row = srow + i * 32;
      gload_lds16(A + (size_t)(m0 + row) * KDIM + kt + sc_,
                  (char*)la + (size_t)idx * 16);
      gload_lds16(BT + (size_t)(n0 + row) * KDIM + kt + sc_,
                  (char*)lb + (size_t)idx * 16);
    }
    __syncthreads();
#pragma unroll
    for (int kk = 0; kk < 2; ++kk) {
      s16x8 af[4], bf[4];
#pragma unroll
      for (int mi = 0; mi < 4; ++mi) {
        int R = wr + mi * 16 + fr;
        af[mi] = *(const s16x8*)((const unsigned short*)la + R * 64 + ((((kk << 2) | g)) ^ (R & 7)) * 8);
      }
#pragma unroll
      for (int ni = 0; ni < 4; ++ni) {
        int R = wc + ni * 16 + fr;
        bf[ni] = *(const s16x8*)((const unsigned short*)lb + R * 64 + ((((kk << 2) | g)) ^ (R & 7)) * 8);
      }
#pragma unroll
      for (int mi = 0; mi < 4; ++mi)
#pragma unroll
        for (int ni = 0; ni < 4; ++ni) acc[mi][ni] = MFMA16(af[mi], bf[ni], acc[mi][ni]);
    }
  }
  int rbase = m0 + wr + rg;
#pragma unroll
  for (int ni = 0; ni < 4; ++ni) {
    int gn = n0 + wc + ni * 16 + fr;
#pragma unroll
    for (int mi = 0; mi < 4; ++mi)
#pragma unroll
      for (int r = 0; r < 4; ++r)
        C[(size_t)(rbase + mi * 16 + r) * 2048 + gn] = acc[mi][ni][r];
  }
}

// ---------------- RoPE on [rows][128] contiguous layout ----------------
__global__ __launch_bounds__(256) void rope2(
    unsigned short* __restrict__ X, const float* __restrict__ tbl) {
  __shared__ __align__(16) unsigned short xs[32][136];
  int tid = threadIdx.x;
  size_t r0 = (size_t)blockIdx.x * 32;
#pragma unroll
  for (int i = 0; i < 2; ++i) {
    int idx = tid + i * 256;
    int pr = idx >> 4, seg = idx & 15;
    *(s16x8*)(&xs[pr][seg * 8]) = *(const s16x8*)(X + (r0 + pr) * 128 + seg * 8);
  }
  __syncthreads();
  int pr = tid >> 3, jb = (tid & 7) * 8;
  size_t row = r0 + pr;
  int s = (int)(row & (SEQ - 1));
  s16x8 o0, o1;
#pragma unroll
  for (int j0 = 0; j0 < 8; ++j0) {
    int j = jb + j0;
    float c  = tbl[(s * 64 + j) * 2];
    float sn = tbl[(s * 64 + j) * 2 + 1];
    float xj   = bf2f(xs[pr][j]);
    float xj64 = bf2f(xs[pr][j + 64]);
    float x2j  = bf2f(xs[pr][2 * j]);
    float x2j1 = bf2f(xs[pr][2 * j + 1]);
    o0[j0] = (short)f2bf(xj * c - x2j1 * sn);
    o1[j0] = (short)f2bf(xj64 * c + x2j * sn);
  }
  unsigned short* xp = X + row * 128;
  *(s16x8*)(xp + jb)      = o0;
  *(s16x8*)(xp + 64 + jb) = o1;
}

// ---------------- Flash attention v9: V direct from L2, 1 barrier/tile, 3 blk/CU ----------------
// grid 512 x 512thr: XCD (l&7) owns one (b,kvh); slot: hloc(2b) + p(4b).
// Waves 0-3 -> qt=31-p; waves 4-7 -> qt=p. K double-buffered in LDS (44KB tot).
__global__ __launch_bounds__(512, 2) void attn_fwd(
    const unsigned short* __restrict__ Q, const unsigned short* __restrict__ K,
    const unsigned short* __restrict__ VT, const float* __restrict__ mask,
    unsigned short* __restrict__ O) {
  __shared__ __align__(16) unsigned short kt_[2][64][136];
  __shared__ __align__(16) unsigned short pt_[8][16][36];

  int tid = threadIdx.x, lane = tid & 63, w = tid >> 6;
  int l = blockIdx.x;
  int grp = l & 7, slot = l >> 3;
  int hloc = slot & 3, p = slot >> 2;            // p 0..15
  int b = grp >> 2, kvh = grp & 3, h = kvh * 4 + hloc;
  int half = w >> 2, wsub = w & 3;
  int qt = half ? p : 31 - p;
  int qw = qt * 64 + wsub * 16;                  // wave's 16 q-rows
  int fr = lane & 15, g = lane >> 4, kg = g * 8, rg = g * 4;

  const unsigned short* Qb = Q + (size_t)(b * NH + h) * SEQ * HD;
  const unsigned short* Kb = K + (size_t)(b * NKV + kvh) * SEQ * HD;
  const unsigned short* Vb = VT + (size_t)(b * NKV + kvh) * HD * SEQ;
  const float* mb = mask + (size_t)b * SEQ;

  // K staging geometry (512 threads, 2 chunks each)
  int krow = tid >> 4, kpos = (tid & 15) * 8;    // K rows krow, krow+32

  const float sc2 = 0.12751744584812722f;        // 1/sqrt(128) * log2(e)
  const float L2E = 1.44269504088896f;
  int bS = b * SEQ;
  int ntiles = 32 - p;                           // qtA + 1

  s16x8 aq[4];
#pragma unroll
  for (int dc = 0; dc < 4; ++dc)
    aq[dc] = *(const s16x8*)(Qb + (size_t)(qw + fr) * HD + dc * 32 + kg);

  f32x4 oacc[8] = {};
  float m_r = -3e38f, l_r = 0.f;

  s16x8 kreg[2];
  // prologue: K(0) -> kt_[0]
  kreg[0] = *(const s16x8*)(Kb + (size_t)krow * HD + kpos);
  kreg[1] = *(const s16x8*)(Kb + (size_t)(krow + 32) * HD + kpos);
  *(s16x8*)(&kt_[0][krow][kpos])      = kreg[0];
  *(s16x8*)(&kt_[0][krow + 32][kpos]) = kreg[1];
  BARRIER_LDS();

  int cur = 0;
  for (int t = 0; t < ntiles; ++t) {
    int kv0 = t * 64;
    bool notlast = (t + 1 < ntiles);
    bool active = (kv0 <= qw + 15);              // wave-uniform
    bool diag   = (kv0 + 63 > qw);

    // issue K(t+1) -> regs (stays in flight across the barrier)
    if (notlast) {
      kreg[0] = *(const s16x8*)(Kb + (size_t)(kv0 + 64 + krow) * HD + kpos);
      kreg[1] = *(const s16x8*)(Kb + (size_t)(kv0 + 96 + krow) * HD + kpos);
    }

    f32x4 sf[4];
    if (active) {
      // QK^T: S^T element (kv = kv0+mk*16+rg+r, q = qw+fr)
      __builtin_amdgcn_s_setprio(1);
#pragma unroll
      for (int mk = 0; mk < 4; ++mk) {
        s16x8 ak[4];
#pragma unroll
        for (int dc = 0; dc < 4; ++dc)
          ak[dc] = *(const s16x8*)(&kt_[cur][mk * 16 + fr][dc * 32 + kg]);
        sf[mk] = f32x4{0.f, 0.f, 0.f, 0.f};
#pragma unroll
        for (int dc = 0; dc < 4; ++dc)
          sf[mk] = MFMA16(ak[dc], aq[dc], sf[mk]);
      }
      __builtin_amdgcn_s_setprio(0);

      // scale + mask (log2 domain); causal select only on diagonal tile
#pragma unroll
      for (int mk = 0; mk < 4; ++mk) {
        float4 mv = *(const float4*)(mb + kv0 + mk * 16 + rg);
        float mvr[4] = {mv.x * L2E, mv.y * L2E, mv.z * L2E, mv.w * L2E};
        if (diag) {
#pragma unroll
          for (int r = 0; r < 4; ++r) {
            int kv = kv0 + mk * 16 + rg + r;
            float v = sf[mk][r] * sc2 + mvr[r];
            sf[mk][r] = (kv <= qw + fr) ? v : -3e38f;
          }
        } else {
#pragma unroll
          for (int r = 0; r < 4; ++r)
            sf[mk][r] = sf[mk][r] * sc2 + mvr[r];
        }
      }

      // online softmax (exp2 domain); tree max
      float pm01a = fmaxf(sf[0][0], sf[0][1]), pm01b = fmaxf(sf[0][2], sf[0][3]);
      float pm11a = fmaxf(sf[1][0], sf[1][1]), pm11b = fmaxf(sf[1][2], sf[1][3]);
      float pm21a = fmaxf(sf[2][0], sf[2][1]), pm21b = fmaxf(sf[2][2], sf[2][3]);
      float pm31a = fmaxf(sf[3][0], sf[3][1]), pm31b = fmaxf(sf[3][2], sf[3][3]);
      float pm0 = fmaxf(pm01a, pm01b), pm1 = fmaxf(pm11a, pm11b);
      float pm2 = fmaxf(pm21a, pm21b), pm3 = fmaxf(pm31a, pm31b);
      float pm = fmaxf(fmaxf(pm0, pm1), fmaxf(pm2, pm3));
      pm = fmaxf(pm, __shfl_xor(pm, 16, 64));
      pm = fmaxf(pm, __shfl_xor(pm, 32, 64));
      if (!__all(pm - m_r <= 8.0f)) {
        float mo = m_r;
        float mn = fmaxf(mo, pm);
        float al = exp2f(mo - mn);
        m_r = mn;
        l_r *= al;
#pragma unroll
        for (int r = 0; r < 4; ++r) {
          float ar = __shfl(al, rg + r, 16);
#pragma unroll
          for (int od = 0; od < 8; ++od) oacc[od][r] *= ar;
        }
      }
      float rs = 0.f;
#pragma unroll
      for (int mk = 0; mk < 4; ++mk)
#pragma unroll
        for (int r = 0; r < 4; ++r) {
          float ppv = exp2f(sf[mk][r] - m_r);
          sf[mk][r] = ppv;
          rs += ppv;
        }
      rs += __shfl_xor(rs, 16, 64);
      rs += __shfl_xor(rs, 32, 64);
      l_r += rs;
    }

    // write K(t+1) into the other buffer (pre-barrier; reads are post-barrier)
    if (notlast) {
      *(s16x8*)(&kt_[cur ^ 1][krow][kpos])      = kreg[0];
      *(s16x8*)(&kt_[cur ^ 1][krow + 32][kpos]) = kreg[1];
    }

    if (active) {
      // PV: P -> pt_ (per-wave, same-wave read); V^T direct from global (L1/L2)
#pragma unroll
      for (int kk = 0; kk < 2; ++kk) {
#pragma unroll
        for (int mh = 0; mh < 2; ++mh) {
          int mk = kk * 2 + mh;
          s16x4 pk;
#pragma unroll
          for (int r = 0; r < 4; ++r) pk[r] = (short)f2bf(sf[mk][r]);
          *(s16x4*)(&pt_[w][fr][mh * 16 + rg]) = pk;
        }
        s16x8 ap = *(const s16x8*)(&pt_[w][fr][kg]);
        __builtin_amdgcn_s_setprio(1);
#pragma unroll
        for (int od = 0; od < 8; ++od) {
          s16x8 bv = *(const s16x8*)(Vb + (size_t)(od * 16 + fr) * SEQ + kv0 + kk * 32 + kg);
          oacc[od] = MFMA16(ap, bv, oacc[od]);
        }
        __builtin_amdgcn_s_setprio(0);
      }
    }
    BARRIER_LDS();  // single barrier: kt_[cur^1]=K(t+1) visible; kt_[cur] reads done
    cur ^= 1;
  }

  // epilogue: O element (q = qw+rg+r, d = od*16+fr)
  float iv = 1.0f / l_r;
  float ivr[4];
#pragma unroll
  for (int r = 0; r < 4; ++r) ivr[r] = __shfl(iv, rg + r, 16);
#pragma unroll
  for (int r = 0; r < 4; ++r) {
    unsigned short* op = O + (size_t)(bS + qw + rg + r) * 2048 + h * 128 + fr;
#pragma unroll
    for (int od = 0; od < 8; ++od)
      op[od * 16] = f2bf(oacc[od][r] * ivr[r]);
  }
}

extern "C" void kernel_launch(void* const* d_in, const int* in_sizes, int n_in,
                              void* d_out, int out_size, void* d_ws, size_t ws_size,
                              hipStream_t stream) {
  const float* hidden = (const float*)d_in[0];
  const float* mask   = (const float*)d_in[1];
  const float* Wq     = (const float*)d_in[2];
  const float* Wk     = (const float*)d_in[3];
  const float* Wv     = (const float*)d_in[4];
  const float* Wo     = (const float*)d_in[5];
  float* out = (float*)d_out;

  char* ws = (char*)d_ws;
  unsigned short* BT  = (unsigned short*)(ws);                 // 3072x2048 bf16
  unsigned short* WoT = (unsigned short*)(ws + 12582912);      // 2048x2048 bf16
  unsigned short* Qb  = (unsigned short*)(ws + 20971520);      // [B][NH][S][HD]
  unsigned short* Kb  = (unsigned short*)(ws + 37748736);      // [B][NKV][S][HD]
  unsigned short* VT  = (unsigned short*)(ws + 41943040);      // [B][NKV][HD][S]
  unsigned short* AO  = (unsigned short*)(ws + 46137344);      // [MROWS][2048] bf16
  float*          tbl = (float*)(ws + 62914560);               // [S][64][2] f32
  unsigned short* Ab  = AO;  // hidden as bf16; dead before attn writes AO

  conv_bf16<<<MROWS * KDIM / (256 * 8), 256, 0, stream>>>(hidden, Ab);
  transpose_convert<<<dim3(64, 64), 256, 0, stream>>>(Wq, BT, KDIM, 2048);
  transpose_convert<<<dim3(16, 64), 256, 0, stream>>>(Wk, BT + (size_t)2048 * KDIM, KDIM, 512);
  transpose_convert<<<dim3(16, 64), 256, 0, stream>>>(Wv, BT + (size_t)2560 * KDIM, KDIM, 512);
  transpose_convert<<<dim3(64, 64), 256, 0, stream>>>(Wo, WoT, KDIM, 2048);
  rope_table_kernel<<<512, 256, 0, stream>>>(tbl);

  gemm_qkv<<<dim3(768), 256, 0, stream>>>(Ab, BT, Qb, Kb, VT);
  rope2<<<(BATCH * NH * SEQ) / 32, 256, 0, stream>>>(Qb, tbl);
  rope2<<<(BATCH * NKV * SEQ) / 32, 256, 0, stream>>>(Kb, tbl);
  attn_fwd<<<dim3(512), 512, 0, stream>>>(Qb, Kb, VT, mask, AO);
  gemm_out<<<dim3(512), 256, 0, stream>>>(AO, WoT, out);
}

// Round 11
// 229.276 us; speedup vs baseline: 1.6755x; 1.6508x over previous
//
#include <hip/hip_runtime.h>
#include <hip/hip_bf16.h>

#define BATCH 2
#define SEQ   2048
#define NH    16
#define NKV   4
#define HD    128
#define KDIM  2048
#define MROWS 4096
#define NQKV  3072

typedef __attribute__((ext_vector_type(8))) short  s16x8;
typedef __attribute__((ext_vector_type(4))) short  s16x4;
typedef __attribute__((ext_vector_type(4))) float  f32x4;
typedef __attribute__((ext_vector_type(8))) __bf16 b16x8;

// barrier that drains LDS ops only -- leaves global prefetch loads in flight
#define BARRIER_LDS() do { \
    asm volatile("s_waitcnt lgkmcnt(0)" ::: "memory"); \
    __builtin_amdgcn_s_barrier(); \
  } while (0)

__device__ __forceinline__ unsigned short f2bf(float f) {
  __hip_bfloat16 h = __float2bfloat16(f);
  return *reinterpret_cast<unsigned short*>(&h);
}
__device__ __forceinline__ float bf2f(unsigned short h) {
  union { unsigned int u; float f; } x; x.u = ((unsigned int)h) << 16;
  return x.f;
}

__device__ __forceinline__ f32x4 MFMA16(s16x8 a, s16x8 b, f32x4 c) {
  return __builtin_amdgcn_mfma_f32_16x16x32_bf16(
      __builtin_bit_cast(b16x8, a), __builtin_bit_cast(b16x8, b), c, 0, 0, 0);
}

__device__ __forceinline__ void gload_lds16(const void* g, void* lds) {
  __builtin_amdgcn_global_load_lds(
      (const __attribute__((address_space(1))) void*)g,
      (__attribute__((address_space(3))) void*)lds, 16, 0, 0);
}

// ---------------- W (KxN f32) -> WT (NxK bf16) ----------------
__global__ __launch_bounds__(256) void transpose_convert(
    const float* __restrict__ W, unsigned short* __restrict__ WT, int Kd, int Nd) {
  __shared__ float tile[32][33];
  int n0 = blockIdx.x * 32, k0 = blockIdx.y * 32;
  int tx = threadIdx.x & 31, ty = threadIdx.x >> 5;
#pragma unroll
  for (int i = 0; i < 4; ++i)
    tile[ty + i * 8][tx] = W[(size_t)(k0 + ty + i * 8) * Nd + n0 + tx];
  __syncthreads();
#pragma unroll
  for (int i = 0; i < 4; ++i)
    WT[(size_t)(n0 + ty + i * 8) * Kd + k0 + tx] = f2bf(tile[tx][ty + i * 8]);
}

// ---------------- f32 -> bf16 bulk convert ----------------
__global__ __launch_bounds__(256) void conv_bf16(
    const float* __restrict__ X, unsigned short* __restrict__ Y) {
  int i = blockIdx.x * 256 + threadIdx.x;
  const float4 a = ((const float4*)X)[2 * i];
  const float4 b = ((const float4*)X)[2 * i + 1];
  s16x8 o;
  o[0] = (short)f2bf(a.x); o[1] = (short)f2bf(a.y);
  o[2] = (short)f2bf(a.z); o[3] = (short)f2bf(a.w);
  o[4] = (short)f2bf(b.x); o[5] = (short)f2bf(b.y);
  o[6] = (short)f2bf(b.z); o[7] = (short)f2bf(b.w);
  ((s16x8*)Y)[i] = o;
}

// ---------------- RoPE cos/sin table ----------------
__global__ __launch_bounds__(256) void rope_table_kernel(float* __restrict__ tbl) {
  int i = blockIdx.x * 256 + threadIdx.x;
  int s = i >> 6, j = i & 63;
  float inv = powf(10000.0f, -(float)(2 * j) * (1.0f / 128.0f));
  float f = (float)s * inv;
  tbl[2 * i]     = cosf(f);
  tbl[2 * i + 1] = sinf(f);
}

// ---------------- QKV GEMM (bf16 x bf16); per-head epilogue; XCD-swizzled grid ----------------
__global__ __launch_bounds__(256) void gemm_qkv(
    const unsigned short* __restrict__ A, const unsigned short* __restrict__ BT,
    unsigned short* __restrict__ Qo, unsigned short* __restrict__ Ko,
    unsigned short* __restrict__ Vo) {
  __shared__ __align__(16) unsigned short la[128][32];
  __shared__ __align__(16) unsigned short lb[128][32];
  int tid = threadIdx.x, lane = tid & 63, w = tid >> 6;
  int lin = blockIdx.x;
  int swz = (lin & 7) * 96 + (lin >> 3);
  int bx = swz % 24, by = swz / 24;
  int m0 = by * 128, n0 = bx * 128;
  int wr = (w >> 1) * 64, wc = (w & 1) * 64;
  int fr = lane & 15, kg = (lane >> 4) * 8, rg = (lane >> 4) * 4;
  f32x4 acc[4][4] = {};
  for (int kt = 0; kt < KDIM; kt += 32) {
    __syncthreads();
#pragma unroll
    for (int i = 0; i < 2; ++i) {
      int idx = tid + i * 256;
      int row = idx >> 2, seg = idx & 3;
      gload_lds16(A + (size_t)(m0 + row) * KDIM + kt + seg * 8,
                  (char*)la + (size_t)(i * 256 + w * 64) * 16);
      gload_lds16(BT + (size_t)(n0 + row) * KDIM + kt + seg * 8,
                  (char*)lb + (size_t)(i * 256 + w * 64) * 16);
    }
    __syncthreads();
    s16x8 af[4], bf[4];
#pragma unroll
    for (int mi = 0; mi < 4; ++mi) af[mi] = *(const s16x8*)(&la[wr + mi * 16 + fr][kg]);
#pragma unroll
    for (int ni = 0; ni < 4; ++ni) bf[ni] = *(const s16x8*)(&lb[wc + ni * 16 + fr][kg]);
#pragma unroll
    for (int mi = 0; mi < 4; ++mi)
#pragma unroll
      for (int ni = 0; ni < 4; ++ni) acc[mi][ni] = MFMA16(af[mi], bf[ni], acc[mi][ni]);
  }
  int rbase = m0 + wr + rg;
#pragma unroll
  for (int ni = 0; ni < 4; ++ni) {
    int gn = n0 + wc + ni * 16 + fr;
    if (gn < 2048) {
      int hh = gn >> 7, d = gn & 127;
#pragma unroll
      for (int mi = 0; mi < 4; ++mi)
#pragma unroll
        for (int r = 0; r < 4; ++r) {
          int grow = rbase + mi * 16 + r;
          int bb = grow >> 11, ss = grow & 2047;
          Qo[((size_t)(bb * NH + hh) * SEQ + ss) * HD + d] = f2bf(acc[mi][ni][r]);
        }
    } else if (gn < 2560) {
      int c = gn - 2048, kvh = c >> 7, d = c & 127;
#pragma unroll
      for (int mi = 0; mi < 4; ++mi)
#pragma unroll
        for (int r = 0; r < 4; ++r) {
          int grow = rbase + mi * 16 + r;
          int bb = grow >> 11, ss = grow & 2047;
          Ko[((size_t)(bb * NKV + kvh) * SEQ + ss) * HD + d] = f2bf(acc[mi][ni][r]);
        }
    } else {
      int c = gn - 2560, kvh = c >> 7, d = c & 127;
#pragma unroll
      for (int mi = 0; mi < 4; ++mi) {
        int grow0 = rbase + mi * 16;
        int bb = grow0 >> 11, ss = grow0 & 2047;
        s16x4 pk;
#pragma unroll
        for (int r = 0; r < 4; ++r) pk[r] = (short)f2bf(acc[mi][ni][r]);
        *(s16x4*)(Vo + ((size_t)(bb * NKV + kvh) * HD + d) * SEQ + ss) = pk;
      }
    }
  }
}

// ---------------- O-proj GEMM; XCD-swizzled grid ----------------
__global__ __launch_bounds__(256) void gemm_out(
    const unsigned short* __restrict__ A, const unsigned short* __restrict__ BT,
    float* __restrict__ C) {
  __shared__ __align__(16) unsigned short la[128][32];
  __shared__ __align__(16) unsigned short lb[128][32];
  int tid = threadIdx.x, lane = tid & 63, w = tid >> 6;
  int lin = blockIdx.x;
  int swz = (lin & 7) * 64 + (lin >> 3);
  int bx = swz % 16, by = swz / 16;
  int m0 = by * 128, n0 = bx * 128;
  int wr = (w >> 1) * 64, wc = (w & 1) * 64;
  int fr = lane & 15, kg = (lane >> 4) * 8, rg = (lane >> 4) * 4;
  f32x4 acc[4][4] = {};
  for (int kt = 0; kt < KDIM; kt += 32) {
    __syncthreads();
#pragma unroll
    for (int i = 0; i < 2; ++i) {
      int idx = tid + i * 256;
      int row = idx >> 2, seg = idx & 3;
      gload_lds16(A + (size_t)(m0 + row) * KDIM + kt + seg * 8,
                  (char*)la + (size_t)(i * 256 + w * 64) * 16);
      gload_lds16(BT + (size_t)(n0 + row) * KDIM + kt + seg * 8,
                  (char*)lb + (size_t)(i * 256 + w * 64) * 16);
    }
    __syncthreads();
    s16x8 af[4], bf[4];
#pragma unroll
    for (int mi = 0; mi < 4; ++mi) af[mi] = *(const s16x8*)(&la[wr + mi * 16 + fr][kg]);
#pragma unroll
    for (int ni = 0; ni < 4; ++ni) bf[ni] = *(const s16x8*)(&lb[wc + ni * 16 + fr][kg]);
#pragma unroll
    for (int mi = 0; mi < 4; ++mi)
#pragma unroll
      for (int ni = 0; ni < 4; ++ni) acc[mi][ni] = MFMA16(af[mi], bf[ni], acc[mi][ni]);
  }
  int rbase = m0 + wr + rg;
#pragma unroll
  for (int ni = 0; ni < 4; ++ni) {
    int gn = n0 + wc + ni * 16 + fr;
#pragma unroll
    for (int mi = 0; mi < 4; ++mi)
#pragma unroll
      for (int r = 0; r < 4; ++r)
        C[(size_t)(rbase + mi * 16 + r) * 2048 + gn] = acc[mi][ni][r];
  }
}

// ---------------- RoPE on [rows][128] contiguous layout ----------------
__global__ __launch_bounds__(256) void rope2(
    unsigned short* __restrict__ X, const float* __restrict__ tbl) {
  __shared__ __align__(16) unsigned short xs[32][136];
  int tid = threadIdx.x;
  size_t r0 = (size_t)blockIdx.x * 32;
#pragma unroll
  for (int i = 0; i < 2; ++i) {
    int idx = tid + i * 256;
    int pr = idx >> 4, seg = idx & 15;
    *(s16x8*)(&xs[pr][seg * 8]) = *(const s16x8*)(X + (r0 + pr) * 128 + seg * 8);
  }
  __syncthreads();
  int pr = tid >> 3, jb = (tid & 7) * 8;
  size_t row = r0 + pr;
  int s = (int)(row & (SEQ - 1));
  s16x8 o0, o1;
#pragma unroll
  for (int j0 = 0; j0 < 8; ++j0) {
    int j = jb + j0;
    float c  = tbl[(s * 64 + j) * 2];
    float sn = tbl[(s * 64 + j) * 2 + 1];
    float xj   = bf2f(xs[pr][j]);
    float xj64 = bf2f(xs[pr][j + 64]);
    float x2j  = bf2f(xs[pr][2 * j]);
    float x2j1 = bf2f(xs[pr][2 * j + 1]);
    o0[j0] = (short)f2bf(xj * c - x2j1 * sn);
    o1[j0] = (short)f2bf(xj64 * c + x2j * sn);
  }
  unsigned short* xp = X + row * 128;
  *(s16x8*)(xp + jb)      = o0;
  *(s16x8*)(xp + 64 + jb) = o1;
}

// ---------------- Flash attention v11: 1024 unfolded blocks, 39.4KB LDS, 4 blk/CU ----------------
// grid 1024 x 256thr: XCD (l&7) owns one (b,kvh); slot: hloc(2b) + descending qt(5b).
// 4 waves x 16 q-rows = 64-row q-tile per block; single-K LDS buffer, 2 barriers/tile;
// reg-staged async K/V prefetch (loads stay in flight across BARRIER_LDS).
__global__ __launch_bounds__(256, 2) void attn_fwd(
    const unsigned short* __restrict__ Q, const unsigned short* __restrict__ K,
    const unsigned short* __restrict__ VT, const float* __restrict__ mask,
    unsigned short* __restrict__ O) {
  __shared__ __align__(16) unsigned short kt_[64][136];
  __shared__ __align__(16) unsigned short vt_[128][68];
  __shared__ __align__(16) unsigned short pt_[4][16][36];

  int tid = threadIdx.x, lane = tid & 63, w = tid >> 6;
  int l = blockIdx.x;
  int grp = l & 7, slot = l >> 3;
  int hloc = slot & 3, qt = 31 - (slot >> 2);    // big q-tiles dispatch first
  int b = grp >> 2, kvh = grp & 3, h = kvh * 4 + hloc;
  int qbase = qt * 64;
  int qw = qbase + w * 16;                       // wave's 16 q-rows
  int fr = lane & 15, g = lane >> 4, kg = g * 8, rg = g * 4;

  const unsigned short* Qb = Q + (size_t)(b * NH + h) * SEQ * HD;
  const unsigned short* Kb = K + (size_t)(b * NKV + kvh) * SEQ * HD;
  const unsigned short* Vb = VT + (size_t)(b * NKV + kvh) * HD * SEQ;
  const float* mb = mask + (size_t)b * SEQ;

  int krow = tid >> 4, kpos = (tid & 15) * 8;
  const float sc2 = 0.12751744584812722f;        // 1/sqrt(128) * log2(e)
  const float L2E = 1.44269504088896f;
  int bS = b * SEQ;
  int ntiles = qt + 1;

  s16x8 aq[4];
#pragma unroll
  for (int dc = 0; dc < 4; ++dc)
    aq[dc] = *(const s16x8*)(Qb + (size_t)(qw + fr) * HD + dc * 32 + kg);

  f32x4 oacc[8] = {};
  float m_r = -3e38f, l_r = 0.f;

  s16x8 kreg[4], vreg[4];
  // prologue: K(0) -> kt_, V(0) -> vreg
#pragma unroll
  for (int i = 0; i < 4; ++i)
    kreg[i] = *(const s16x8*)(Kb + (size_t)(krow + i * 16) * HD + kpos);
#pragma unroll
  for (int i = 0; i < 4; ++i) {
    int c = tid + 256 * i;
    vreg[i] = *(const s16x8*)(Vb + (size_t)(c >> 3) * SEQ + (c & 7) * 8);
  }
#pragma unroll
  for (int i = 0; i < 4; ++i)
    *(s16x8*)(&kt_[krow + i * 16][kpos]) = kreg[i];
  BARRIER_LDS();

  for (int t = 0; t < ntiles; ++t) {
    int kv0 = t * 64;
    bool notlast = (t + 1 < ntiles);
    bool diag = (kv0 + 63 > qw);                 // wave-uniform; final tile only

    // write V(t) -> LDS (vt_ free since B2 of prev tile)
#pragma unroll
    for (int i = 0; i < 4; ++i) {
      int c = tid + 256 * i;
      *(s16x8*)(&vt_[c >> 3][(c & 7) * 8]) = vreg[i];
    }
    // issue K(t+1) -> regs (stays in flight across B1)
    if (notlast) {
#pragma unroll
      for (int i = 0; i < 4; ++i)
        kreg[i] = *(const s16x8*)(Kb + (size_t)(kv0 + 64 + krow + i * 16) * HD + kpos);
    }

    // QK^T: S^T element (kv = kv0+mk*16+rg+r, q = qw+fr)
    f32x4 sf[4];
    __builtin_amdgcn_s_setprio(1);
#pragma unroll
    for (int mk = 0; mk < 4; ++mk) {
      s16x8 ak[4];
#pragma unroll
      for (int dc = 0; dc < 4; ++dc)
        ak[dc] = *(const s16x8*)(&kt_[mk * 16 + fr][dc * 32 + kg]);
      sf[mk] = f32x4{0.f, 0.f, 0.f, 0.f};
#pragma unroll
      for (int dc = 0; dc < 4; ++dc)
        sf[mk] = MFMA16(ak[dc], aq[dc], sf[mk]);
    }
    __builtin_amdgcn_s_setprio(0);

    // scale + mask (log2 domain); causal select only on diagonal tile
#pragma unroll
    for (int mk = 0; mk < 4; ++mk) {
      float4 mv = *(const float4*)(mb + kv0 + mk * 16 + rg);
      float mvr[4] = {mv.x * L2E, mv.y * L2E, mv.z * L2E, mv.w * L2E};
      if (diag) {
#pragma unroll
        for (int r = 0; r < 4; ++r) {
          int kv = kv0 + mk * 16 + rg + r;
          float v = sf[mk][r] * sc2 + mvr[r];
          sf[mk][r] = (kv <= qw + fr) ? v : -3e38f;
        }
      } else {
#pragma unroll
        for (int r = 0; r < 4; ++r)
          sf[mk][r] = sf[mk][r] * sc2 + mvr[r];
      }
    }

    // online softmax (exp2 domain); tree max
    float pm01a = fmaxf(sf[0][0], sf[0][1]), pm01b = fmaxf(sf[0][2], sf[0][3]);
    float pm11a = fmaxf(sf[1][0], sf[1][1]), pm11b = fmaxf(sf[1][2], sf[1][3]);
    float pm21a = fmaxf(sf[2][0], sf[2][1]), pm21b = fmaxf(sf[2][2], sf[2][3]);
    float pm31a = fmaxf(sf[3][0], sf[3][1]), pm31b = fmaxf(sf[3][2], sf[3][3]);
    float pm0 = fmaxf(pm01a, pm01b), pm1 = fmaxf(pm11a, pm11b);
    float pm2 = fmaxf(pm21a, pm21b), pm3 = fmaxf(pm31a, pm31b);
    float pm = fmaxf(fmaxf(pm0, pm1), fmaxf(pm2, pm3));
    pm = fmaxf(pm, __shfl_xor(pm, 16, 64));
    pm = fmaxf(pm, __shfl_xor(pm, 32, 64));
    if (!__all(pm - m_r <= 8.0f)) {
      float mo = m_r;
      float mn = fmaxf(mo, pm);
      float al = exp2f(mo - mn);
      m_r = mn;
      l_r *= al;
#pragma unroll
      for (int r = 0; r < 4; ++r) {
        float ar = __shfl(al, rg + r, 16);
#pragma unroll
        for (int od = 0; od < 8; ++od) oacc[od][r] *= ar;
      }
    }
    float rs = 0.f;
#pragma unroll
    for (int mk = 0; mk < 4; ++mk)
#pragma unroll
      for (int r = 0; r < 4; ++r) {
        float ppv = exp2f(sf[mk][r] - m_r);
        sf[mk][r] = ppv;
        rs += ppv;
      }
    rs += __shfl_xor(rs, 16, 64);
    rs += __shfl_xor(rs, 32, 64);
    l_r += rs;

    BARRIER_LDS();  // B1: kt_ reads done across waves; vt_ writes visible

    // write K(t+1) into kt_; issue V(t+1) loads (in flight across B2)
    if (notlast) {
#pragma unroll
      for (int i = 0; i < 4; ++i)
        *(s16x8*)(&kt_[krow + i * 16][kpos]) = kreg[i];
#pragma unroll
      for (int i = 0; i < 4; ++i) {
        int c = tid + 256 * i;
        vreg[i] = *(const s16x8*)(Vb + (size_t)(c >> 3) * SEQ + kv0 + 64 + (c & 7) * 8);
      }
    }

    // PV: P -> pt_ (per-wave, same-wave read), V^T from vt_
#pragma unroll
    for (int kk = 0; kk < 2; ++kk) {
#pragma unroll
      for (int mh = 0; mh < 2; ++mh) {
        int mk = kk * 2 + mh;
        s16x4 pk;
#pragma unroll
        for (int r = 0; r < 4; ++r) pk[r] = (short)f2bf(sf[mk][r]);
        *(s16x4*)(&pt_[w][fr][mh * 16 + rg]) = pk;
      }
      s16x8 ap = *(const s16x8*)(&pt_[w][fr][kg]);
      __builtin_amdgcn_s_setprio(1);
#pragma unroll
      for (int od = 0; od < 8; ++od) {
        s16x8 bv = *(const s16x8*)(&vt_[od * 16 + fr][kk * 32 + kg]);
        oacc[od] = MFMA16(ap, bv, oacc[od]);
      }
      __builtin_amdgcn_s_setprio(0);
    }
    BARRIER_LDS();  // B2: kt_ = K(t+1) visible; vt_ free
  }

  // epilogue: O element (q = qw+rg+r, d = od*16+fr)
  float iv = 1.0f / l_r;
  float ivr[4];
#pragma unroll
  for (int r = 0; r < 4; ++r) ivr[r] = __shfl(iv, rg + r, 16);
#pragma unroll
  for (int r = 0; r < 4; ++r) {
    unsigned short* op = O + (size_t)(bS + qw + rg + r) * 2048 + h * 128 + fr;
#pragma unroll
    for (int od = 0; od < 8; ++od)
      op[od * 16] = f2bf(oacc[od][r] * ivr[r]);
  }
}

extern "C" void kernel_launch(void* const* d_in, const int* in_sizes, int n_in,
                              void* d_out, int out_size, void* d_ws, size_t ws_size,
                              hipStream_t stream) {
  const float* hidden = (const float*)d_in[0];
  const float* mask   = (const float*)d_in[1];
  const float* Wq     = (const float*)d_in[2];
  const float* Wk     = (const float*)d_in[3];
  const float* Wv     = (const float*)d_in[4];
  const float* Wo     = (const float*)d_in[5];
  float* out = (float*)d_out;

  char* ws = (char*)d_ws;
  unsigned short* BT  = (unsigned short*)(ws);                 // 3072x2048 bf16
  unsigned short* WoT = (unsigned short*)(ws + 12582912);      // 2048x2048 bf16
  unsigned short* Qb  = (unsigned short*)(ws + 20971520);      // [B][NH][S][HD]
  unsigned short* Kb  = (unsigned short*)(ws + 37748736);      // [B][NKV][S][HD]
  unsigned short* VT  = (unsigned short*)(ws + 41943040);      // [B][NKV][HD][S]
  unsigned short* AO  = (unsigned short*)(ws + 46137344);      // [MROWS][2048] bf16
  float*          tbl = (float*)(ws + 62914560);               // [S][64][2] f32
  unsigned short* Ab  = AO;  // hidden as bf16; dead before attn writes AO

  conv_bf16<<<MROWS * KDIM / (256 * 8), 256, 0, stream>>>(hidden, Ab);
  transpose_convert<<<dim3(64, 64), 256, 0, stream>>>(Wq, BT, KDIM, 2048);
  transpose_convert<<<dim3(16, 64), 256, 0, stream>>>(Wk, BT + (size_t)2048 * KDIM, KDIM, 512);
  transpose_convert<<<dim3(16, 64), 256, 0, stream>>>(Wv, BT + (size_t)2560 * KDIM, KDIM, 512);
  transpose_convert<<<dim3(64, 64), 256, 0, stream>>>(Wo, WoT, KDIM, 2048);
  rope_table_kernel<<<512, 256, 0, stream>>>(tbl);

  gemm_qkv<<<dim3(768), 256, 0, stream>>>(Ab, BT, Qb, Kb, VT);
  rope2<<<(BATCH * NH * SEQ) / 32, 256, 0, stream>>>(Qb, tbl);
  rope2<<<(BATCH * NKV * SEQ) / 32, 256, 0, stream>>>(Kb, tbl);
  attn_fwd<<<dim3(1024), 256, 0, stream>>>(Qb, Kb, VT, mask, AO);
  gemm_out<<<dim3(512), 256, 0, stream>>>(AO, WoT, out);
}

// Round 12
// 228.363 us; speedup vs baseline: 1.6822x; 1.0040x over previous
//
#include <hip/hip_runtime.h>
#include <hip/hip_bf16.h>

#define BATCH 2
#define SEQ   2048
#define NH    16
#define NKV   4
#define HD    128
#define KDIM  2048
#define MROWS 4096
#define NQKV  3072

typedef __attribute__((ext_vector_type(8))) short  s16x8;
typedef __attribute__((ext_vector_type(4))) short  s16x4;
typedef __attribute__((ext_vector_type(4))) float  f32x4;
typedef __attribute__((ext_vector_type(8))) __bf16 b16x8;

// barrier that drains LDS ops only -- leaves global prefetch loads in flight
#define BARRIER_LDS() do { \
    asm volatile("s_waitcnt lgkmcnt(0)" ::: "memory"); \
    __builtin_amdgcn_s_barrier(); \
  } while (0)

__device__ __forceinline__ unsigned short f2bf(float f) {
  __hip_bfloat16 h = __float2bfloat16(f);
  return *reinterpret_cast<unsigned short*>(&h);
}
__device__ __forceinline__ float bf2f(unsigned short h) {
  union { unsigned int u; float f; } x; x.u = ((unsigned int)h) << 16;
  return x.f;
}

__device__ __forceinline__ f32x4 MFMA16(s16x8 a, s16x8 b, f32x4 c) {
  return __builtin_amdgcn_mfma_f32_16x16x32_bf16(
      __builtin_bit_cast(b16x8, a), __builtin_bit_cast(b16x8, b), c, 0, 0, 0);
}

__device__ __forceinline__ void gload_lds16(const void* g, void* lds) {
  __builtin_amdgcn_global_load_lds(
      (const __attribute__((address_space(1))) void*)g,
      (__attribute__((address_space(3))) void*)lds, 16, 0, 0);
}

// ---------------- fused weight prep: all 4 transposes in one launch ----------------
// regions on blockIdx.x: [0,64) Wq->BT ; [64,80) Wk->BT+2048K ; [80,96) Wv->BT+2560K ; [96,160) Wo->WoT
__global__ __launch_bounds__(256) void prep_weights(
    const float* __restrict__ Wq, const float* __restrict__ Wk,
    const float* __restrict__ Wv, const float* __restrict__ Wo,
    unsigned short* __restrict__ BT, unsigned short* __restrict__ WoT) {
  __shared__ float tile[32][33];
  int bx = blockIdx.x;
  const float* W; unsigned short* WT; int Nd, nb;
  if (bx < 64)       { W = Wq; WT = BT;                          Nd = 2048; nb = bx; }
  else if (bx < 80)  { W = Wk; WT = BT + (size_t)2048 * KDIM;    Nd = 512;  nb = bx - 64; }
  else if (bx < 96)  { W = Wv; WT = BT + (size_t)2560 * KDIM;    Nd = 512;  nb = bx - 80; }
  else               { W = Wo; WT = WoT;                         Nd = 2048; nb = bx - 96; }
  int n0 = nb * 32, k0 = blockIdx.y * 32;
  int tx = threadIdx.x & 31, ty = threadIdx.x >> 5;
#pragma unroll
  for (int i = 0; i < 4; ++i)
    tile[ty + i * 8][tx] = W[(size_t)(k0 + ty + i * 8) * Nd + n0 + tx];
  __syncthreads();
#pragma unroll
  for (int i = 0; i < 4; ++i)
    WT[(size_t)(n0 + ty + i * 8) * KDIM + k0 + tx] = f2bf(tile[tx][ty + i * 8]);
}

// ---------------- f32 -> bf16 bulk convert ----------------
__global__ __launch_bounds__(256) void conv_bf16(
    const float* __restrict__ X, unsigned short* __restrict__ Y) {
  int i = blockIdx.x * 256 + threadIdx.x;
  const float4 a = ((const float4*)X)[2 * i];
  const float4 b = ((const float4*)X)[2 * i + 1];
  s16x8 o;
  o[0] = (short)f2bf(a.x); o[1] = (short)f2bf(a.y);
  o[2] = (short)f2bf(a.z); o[3] = (short)f2bf(a.w);
  o[4] = (short)f2bf(b.x); o[5] = (short)f2bf(b.y);
  o[6] = (short)f2bf(b.z); o[7] = (short)f2bf(b.w);
  ((s16x8*)Y)[i] = o;
}

// ---------------- RoPE cos/sin table ----------------
__global__ __launch_bounds__(256) void rope_table_kernel(float* __restrict__ tbl) {
  int i = blockIdx.x * 256 + threadIdx.x;
  int s = i >> 6, j = i & 63;
  float inv = powf(10000.0f, -(float)(2 * j) * (1.0f / 128.0f));
  float f = (float)s * inv;
  tbl[2 * i]     = cosf(f);
  tbl[2 * i + 1] = sinf(f);
}

// ---------------- QKV GEMM (bf16 x bf16); per-head epilogue; XCD-swizzled grid ----------------
__global__ __launch_bounds__(256) void gemm_qkv(
    const unsigned short* __restrict__ A, const unsigned short* __restrict__ BT,
    unsigned short* __restrict__ Qo, unsigned short* __restrict__ Ko,
    unsigned short* __restrict__ Vo) {
  __shared__ __align__(16) unsigned short la[128][32];
  __shared__ __align__(16) unsigned short lb[128][32];
  int tid = threadIdx.x, lane = tid & 63, w = tid >> 6;
  int lin = blockIdx.x;
  int swz = (lin & 7) * 96 + (lin >> 3);
  int bx = swz % 24, by = swz / 24;
  int m0 = by * 128, n0 = bx * 128;
  int wr = (w >> 1) * 64, wc = (w & 1) * 64;
  int fr = lane & 15, kg = (lane >> 4) * 8, rg = (lane >> 4) * 4;
  f32x4 acc[4][4] = {};
  for (int kt = 0; kt < KDIM; kt += 32) {
    __syncthreads();
#pragma unroll
    for (int i = 0; i < 2; ++i) {
      int idx = tid + i * 256;
      int row = idx >> 2, seg = idx & 3;
      gload_lds16(A + (size_t)(m0 + row) * KDIM + kt + seg * 8,
                  (char*)la + (size_t)(i * 256 + w * 64) * 16);
      gload_lds16(BT + (size_t)(n0 + row) * KDIM + kt + seg * 8,
                  (char*)lb + (size_t)(i * 256 + w * 64) * 16);
    }
    __syncthreads();
    s16x8 af[4], bf[4];
#pragma unroll
    for (int mi = 0; mi < 4; ++mi) af[mi] = *(const s16x8*)(&la[wr + mi * 16 + fr][kg]);
#pragma unroll
    for (int ni = 0; ni < 4; ++ni) bf[ni] = *(const s16x8*)(&lb[wc + ni * 16 + fr][kg]);
#pragma unroll
    for (int mi = 0; mi < 4; ++mi)
#pragma unroll
      for (int ni = 0; ni < 4; ++ni) acc[mi][ni] = MFMA16(af[mi], bf[ni], acc[mi][ni]);
  }
  int rbase = m0 + wr + rg;
#pragma unroll
  for (int ni = 0; ni < 4; ++ni) {
    int gn = n0 + wc + ni * 16 + fr;
    if (gn < 2048) {
      int hh = gn >> 7, d = gn & 127;
#pragma unroll
      for (int mi = 0; mi < 4; ++mi)
#pragma unroll
        for (int r = 0; r < 4; ++r) {
          int grow = rbase + mi * 16 + r;
          int bb = grow >> 11, ss = grow & 2047;
          Qo[((size_t)(bb * NH + hh) * SEQ + ss) * HD + d] = f2bf(acc[mi][ni][r]);
        }
    } else if (gn < 2560) {
      int c = gn - 2048, kvh = c >> 7, d = c & 127;
#pragma unroll
      for (int mi = 0; mi < 4; ++mi)
#pragma unroll
        for (int r = 0; r < 4; ++r) {
          int grow = rbase + mi * 16 + r;
          int bb = grow >> 11, ss = grow & 2047;
          Ko[((size_t)(bb * NKV + kvh) * SEQ + ss) * HD + d] = f2bf(acc[mi][ni][r]);
        }
    } else {
      int c = gn - 2560, kvh = c >> 7, d = c & 127;
#pragma unroll
      for (int mi = 0; mi < 4; ++mi) {
        int grow0 = rbase + mi * 16;
        int bb = grow0 >> 11, ss = grow0 & 2047;
        s16x4 pk;
#pragma unroll
        for (int r = 0; r < 4; ++r) pk[r] = (short)f2bf(acc[mi][ni][r]);
        *(s16x4*)(Vo + ((size_t)(bb * NKV + kvh) * HD + d) * SEQ + ss) = pk;
      }
    }
  }
}

// ---------------- O-proj GEMM; XCD-swizzled grid ----------------
__global__ __launch_bounds__(256) void gemm_out(
    const unsigned short* __restrict__ A, const unsigned short* __restrict__ BT,
    float* __restrict__ C) {
  __shared__ __align__(16) unsigned short la[128][32];
  __shared__ __align__(16) unsigned short lb[128][32];
  int tid = threadIdx.x, lane = tid & 63, w = tid >> 6;
  int lin = blockIdx.x;
  int swz = (lin & 7) * 64 + (lin >> 3);
  int bx = swz % 16, by = swz / 16;
  int m0 = by * 128, n0 = bx * 128;
  int wr = (w >> 1) * 64, wc = (w & 1) * 64;
  int fr = lane & 15, kg = (lane >> 4) * 8, rg = (lane >> 4) * 4;
  f32x4 acc[4][4] = {};
  for (int kt = 0; kt < KDIM; kt += 32) {
    __syncthreads();
#pragma unroll
    for (int i = 0; i < 2; ++i) {
      int idx = tid + i * 256;
      int row = idx >> 2, seg = idx & 3;
      gload_lds16(A + (size_t)(m0 + row) * KDIM + kt + seg * 8,
                  (char*)la + (size_t)(i * 256 + w * 64) * 16);
      gload_lds16(BT + (size_t)(n0 + row) * KDIM + kt + seg * 8,
                  (char*)lb + (size_t)(i * 256 + w * 64) * 16);
    }
    __syncthreads();
    s16x8 af[4], bf[4];
#pragma unroll
    for (int mi = 0; mi < 4; ++mi) af[mi] = *(const s16x8*)(&la[wr + mi * 16 + fr][kg]);
#pragma unroll
    for (int ni = 0; ni < 4; ++ni) bf[ni] = *(const s16x8*)(&lb[wc + ni * 16 + fr][kg]);
#pragma unroll
    for (int mi = 0; mi < 4; ++mi)
#pragma unroll
      for (int ni = 0; ni < 4; ++ni) acc[mi][ni] = MFMA16(af[mi], bf[ni], acc[mi][ni]);
  }
  int rbase = m0 + wr + rg;
#pragma unroll
  for (int ni = 0; ni < 4; ++ni) {
    int gn = n0 + wc + ni * 16 + fr;
#pragma unroll
    for (int mi = 0; mi < 4; ++mi)
#pragma unroll
      for (int r = 0; r < 4; ++r)
        C[(size_t)(rbase + mi * 16 + r) * 2048 + gn] = acc[mi][ni][r];
  }
}

// ---------------- RoPE on [rows][128]; Q and K fused in one launch ----------------
__global__ __launch_bounds__(256) void rope2(
    unsigned short* __restrict__ Qx, unsigned short* __restrict__ Kx,
    const float* __restrict__ tbl) {
  __shared__ __align__(16) unsigned short xs[32][136];
  int tid = threadIdx.x;
  int bid = blockIdx.x;
  unsigned short* X;
  size_t r0;
  if (bid < 2048) { X = Qx; r0 = (size_t)bid * 32; }
  else            { X = Kx; r0 = (size_t)(bid - 2048) * 32; }
#pragma unroll
  for (int i = 0; i < 2; ++i) {
    int idx = tid + i * 256;
    int pr = idx >> 4, seg = idx & 15;
    *(s16x8*)(&xs[pr][seg * 8]) = *(const s16x8*)(X + (r0 + pr) * 128 + seg * 8);
  }
  __syncthreads();
  int pr = tid >> 3, jb = (tid & 7) * 8;
  size_t row = r0 + pr;
  int s = (int)(row & (SEQ - 1));
  s16x8 o0, o1;
#pragma unroll
  for (int j0 = 0; j0 < 8; ++j0) {
    int j = jb + j0;
    float c  = tbl[(s * 64 + j) * 2];
    float sn = tbl[(s * 64 + j) * 2 + 1];
    float xj   = bf2f(xs[pr][j]);
    float xj64 = bf2f(xs[pr][j + 64]);
    float x2j  = bf2f(xs[pr][2 * j]);
    float x2j1 = bf2f(xs[pr][2 * j + 1]);
    o0[j0] = (short)f2bf(xj * c - x2j1 * sn);
    o1[j0] = (short)f2bf(xj64 * c + x2j * sn);
  }
  unsigned short* xp = X + row * 128;
  *(s16x8*)(xp + jb)      = o0;
  *(s16x8*)(xp + 64 + jb) = o1;
}

// ---------------- Flash attention v12: K+V double-buffered, ONE barrier/tile ----------------
// grid 1024 x 256thr: XCD (l&7) owns one (b,kvh); slot: hloc(2b) + descending qt(5b).
// 4 waves x 16 q-rows; round t: write staged t+1 -> buf[cur^1], issue t+2 -> regs,
// compute QK^T/softmax/PV from buf[cur], one lgkmcnt barrier. Loads span 1 barrier.
__global__ __launch_bounds__(256, 2) void attn_fwd(
    const unsigned short* __restrict__ Q, const unsigned short* __restrict__ K,
    const unsigned short* __restrict__ VT, const float* __restrict__ mask,
    unsigned short* __restrict__ O) {
  __shared__ __align__(16) unsigned short kt_[2][64][136];
  __shared__ __align__(16) unsigned short vt_[2][128][68];
  __shared__ __align__(16) unsigned short pt_[4][16][36];

  int tid = threadIdx.x, lane = tid & 63, w = tid >> 6;
  int l = blockIdx.x;
  int grp = l & 7, slot = l >> 3;
  int hloc = slot & 3, qt = 31 - (slot >> 2);    // big q-tiles dispatch first
  int b = grp >> 2, kvh = grp & 3, h = kvh * 4 + hloc;
  int qbase = qt * 64;
  int qw = qbase + w * 16;                       // wave's 16 q-rows
  int fr = lane & 15, g = lane >> 4, kg = g * 8, rg = g * 4;

  const unsigned short* Qb = Q + (size_t)(b * NH + h) * SEQ * HD;
  const unsigned short* Kb = K + (size_t)(b * NKV + kvh) * SEQ * HD;
  const unsigned short* Vb = VT + (size_t)(b * NKV + kvh) * HD * SEQ;
  const float* mb = mask + (size_t)b * SEQ;

  int krow = tid >> 4, kpos = (tid & 15) * 8;
  int vrow0 = tid >> 3, vcol = (tid & 7) * 8;    // V chunks: c = tid + 256*i
  const float sc2 = 0.12751744584812722f;        // 1/sqrt(128) * log2(e)
  const float L2E = 1.44269504088896f;
  int bS = b * SEQ;
  int ntiles = qt + 1;

  s16x8 aq[4];
#pragma unroll
  for (int dc = 0; dc < 4; ++dc)
    aq[dc] = *(const s16x8*)(Qb + (size_t)(qw + fr) * HD + dc * 32 + kg);

  f32x4 oacc[8] = {};
  float m_r = -3e38f, l_r = 0.f;

  s16x8 kreg[4], vreg[4];
  // prologue: stage tile 0 into buf[0] via regs; then preload tile 1 into regs
#pragma unroll
  for (int i = 0; i < 4; ++i)
    kreg[i] = *(const s16x8*)(Kb + (size_t)(krow + i * 16) * HD + kpos);
#pragma unroll
  for (int i = 0; i < 4; ++i) {
    int c = tid + 256 * i;
    vreg[i] = *(const s16x8*)(Vb + (size_t)(c >> 3) * SEQ + (c & 7) * 8);
  }
#pragma unroll
  for (int i = 0; i < 4; ++i)
    *(s16x8*)(&kt_[0][krow + i * 16][kpos]) = kreg[i];
#pragma unroll
  for (int i = 0; i < 4; ++i) {
    int c = tid + 256 * i;
    *(s16x8*)(&vt_[0][c >> 3][(c & 7) * 8]) = vreg[i];
  }
  if (ntiles > 1) {
#pragma unroll
    for (int i = 0; i < 4; ++i)
      kreg[i] = *(const s16x8*)(Kb + (size_t)(64 + krow + i * 16) * HD + kpos);
#pragma unroll
    for (int i = 0; i < 4; ++i) {
      int c = tid + 256 * i;
      vreg[i] = *(const s16x8*)(Vb + (size_t)(c >> 3) * SEQ + 64 + (c & 7) * 8);
    }
  }
  BARRIER_LDS();

  for (int t = 0; t < ntiles; ++t) {
    int kv0 = t * 64;
    int cur = t & 1;
    bool diag = (t == qt);                       // all waves diag only on final tile

    // write staged K(t+1)/V(t+1) into buf[cur^1]; issue K(t+2)/V(t+2) -> regs
    if (t + 1 < ntiles) {
#pragma unroll
      for (int i = 0; i < 4; ++i)
        *(s16x8*)(&kt_[cur ^ 1][krow + i * 16][kpos]) = kreg[i];
#pragma unroll
      for (int i = 0; i < 4; ++i) {
        int c = tid + 256 * i;
        *(s16x8*)(&vt_[cur ^ 1][c >> 3][(c & 7) * 8]) = vreg[i];
      }
      if (t + 2 < ntiles) {
#pragma unroll
        for (int i = 0; i < 4; ++i)
          kreg[i] = *(const s16x8*)(Kb + (size_t)(kv0 + 128 + krow + i * 16) * HD + kpos);
#pragma unroll
        for (int i = 0; i < 4; ++i) {
          int c = tid + 256 * i;
          vreg[i] = *(const s16x8*)(Vb + (size_t)(c >> 3) * SEQ + kv0 + 128 + (c & 7) * 8);
        }
      }
    }

    // QK^T: S^T element (kv = kv0+mk*16+rg+r, q = qw+fr)
    f32x4 sf[4];
    __builtin_amdgcn_s_setprio(1);
#pragma unroll
    for (int mk = 0; mk < 4; ++mk) {
      s16x8 ak[4];
#pragma unroll
      for (int dc = 0; dc < 4; ++dc)
        ak[dc] = *(const s16x8*)(&kt_[cur][mk * 16 + fr][dc * 32 + kg]);
      sf[mk] = f32x4{0.f, 0.f, 0.f, 0.f};
#pragma unroll
      for (int dc = 0; dc < 4; ++dc)
        sf[mk] = MFMA16(ak[dc], aq[dc], sf[mk]);
    }
    __builtin_amdgcn_s_setprio(0);

    // scale + mask (log2 domain); causal select only on diagonal tile
#pragma unroll
    for (int mk = 0; mk < 4; ++mk) {
      float4 mv = *(const float4*)(mb + kv0 + mk * 16 + rg);
      float mvr[4] = {mv.x * L2E, mv.y * L2E, mv.z * L2E, mv.w * L2E};
      if (diag) {
#pragma unroll
        for (int r = 0; r < 4; ++r) {
          int kv = kv0 + mk * 16 + rg + r;
          float v = sf[mk][r] * sc2 + mvr[r];
          sf[mk][r] = (kv <= qw + fr) ? v : -3e38f;
        }
      } else {
#pragma unroll
        for (int r = 0; r < 4; ++r)
          sf[mk][r] = sf[mk][r] * sc2 + mvr[r];
      }
    }

    // online softmax (exp2 domain); tree max
    float pm01a = fmaxf(sf[0][0], sf[0][1]), pm01b = fmaxf(sf[0][2], sf[0][3]);
    float pm11a = fmaxf(sf[1][0], sf[1][1]), pm11b = fmaxf(sf[1][2], sf[1][3]);
    float pm21a = fmaxf(sf[2][0], sf[2][1]), pm21b = fmaxf(sf[2][2], sf[2][3]);
    float pm31a = fmaxf(sf[3][0], sf[3][1]), pm31b = fmaxf(sf[3][2], sf[3][3]);
    float pm0 = fmaxf(pm01a, pm01b), pm1 = fmaxf(pm11a, pm11b);
    float pm2 = fmaxf(pm21a, pm21b), pm3 = fmaxf(pm31a, pm31b);
    float pm = fmaxf(fmaxf(pm0, pm1), fmaxf(pm2, pm3));
    pm = fmaxf(pm, __shfl_xor(pm, 16, 64));
    pm = fmaxf(pm, __shfl_xor(pm, 32, 64));
    if (!__all(pm - m_r <= 8.0f)) {
      float mo = m_r;
      float mn = fmaxf(mo, pm);
      float al = exp2f(mo - mn);
      m_r = mn;
      l_r *= al;
#pragma unroll
      for (int r = 0; r < 4; ++r) {
        float ar = __shfl(al, rg + r, 16);
#pragma unroll
        for (int od = 0; od < 8; ++od) oacc[od][r] *= ar;
      }
    }
    float rs = 0.f;
#pragma unroll
    for (int mk = 0; mk < 4; ++mk)
#pragma unroll
      for (int r = 0; r < 4; ++r) {
        float ppv = exp2f(sf[mk][r] - m_r);
        sf[mk][r] = ppv;
        rs += ppv;
      }
    rs += __shfl_xor(rs, 16, 64);
    rs += __shfl_xor(rs, 32, 64);
    l_r += rs;

    // PV: P -> pt_ (per-wave, same-wave read), V^T from vt_[cur]
#pragma unroll
    for (int kk = 0; kk < 2; ++kk) {
#pragma unroll
      for (int mh = 0; mh < 2; ++mh) {
        int mk = kk * 2 + mh;
        s16x4 pk;
#pragma unroll
        for (int r = 0; r < 4; ++r) pk[r] = (short)f2bf(sf[mk][r]);
        *(s16x4*)(&pt_[w][fr][mh * 16 + rg]) = pk;
      }
      s16x8 ap = *(const s16x8*)(&pt_[w][fr][kg]);
      __builtin_amdgcn_s_setprio(1);
#pragma unroll
      for (int od = 0; od < 8; ++od) {
        s16x8 bv = *(const s16x8*)(&vt_[cur][od * 16 + fr][kk * 32 + kg]);
        oacc[od] = MFMA16(ap, bv, oacc[od]);
      }
      __builtin_amdgcn_s_setprio(0);
    }

    BARRIER_LDS();  // single barrier: buf[cur^1] staged+visible; buf[cur] reads done
  }

  // epilogue: O element (q = qw+rg+r, d = od*16+fr)
  float iv = 1.0f / l_r;
  float ivr[4];
#pragma unroll
  for (int r = 0; r < 4; ++r) ivr[r] = __shfl(iv, rg + r, 16);
#pragma unroll
  for (int r = 0; r < 4; ++r) {
    unsigned short* op = O + (size_t)(bS + qw + rg + r) * 2048 + h * 128 + fr;
#pragma unroll
    for (int od = 0; od < 8; ++od)
      op[od * 16] = f2bf(oacc[od][r] * ivr[r]);
  }
}

extern "C" void kernel_launch(void* const* d_in, const int* in_sizes, int n_in,
                              void* d_out, int out_size, void* d_ws, size_t ws_size,
                              hipStream_t stream) {
  const float* hidden = (const float*)d_in[0];
  const float* mask   = (const float*)d_in[1];
  const float* Wq     = (const float*)d_in[2];
  const float* Wk     = (const float*)d_in[3];
  const float* Wv     = (const float*)d_in[4];
  const float* Wo     = (const float*)d_in[5];
  float* out = (float*)d_out;

  char* ws = (char*)d_ws;
  unsigned short* BT  = (unsigned short*)(ws);                 // 3072x2048 bf16
  unsigned short* WoT = (unsigned short*)(ws + 12582912);      // 2048x2048 bf16
  unsigned short* Qb  = (unsigned short*)(ws + 20971520);      // [B][NH][S][HD]
  unsigned short* Kb  = (unsigned short*)(ws + 37748736);      // [B][NKV][S][HD]
  unsigned short* VT  = (unsigned short*)(ws + 41943040);      // [B][NKV][HD][S]
  unsigned short* AO  = (unsigned short*)(ws + 46137344);      // [MROWS][2048] bf16
  float*          tbl = (float*)(ws + 62914560);               // [S][64][2] f32
  unsigned short* Ab  = AO;  // hidden as bf16; dead before attn writes AO

  conv_bf16<<<MROWS * KDIM / (256 * 8), 256, 0, stream>>>(hidden, Ab);
  prep_weights<<<dim3(160, 64), 256, 0, stream>>>(Wq, Wk, Wv, Wo, BT, WoT);
  rope_table_kernel<<<512, 256, 0, stream>>>(tbl);

  gemm_qkv<<<dim3(768), 256, 0, stream>>>(Ab, BT, Qb, Kb, VT);
  rope2<<<dim3(2048 + 512), 256, 0, stream>>>(Qb, Kb, tbl);
  attn_fwd<<<dim3(1024), 256, 0, stream>>>(Qb, Kb, VT, mask, AO);
  gemm_out<<<dim3(512), 256, 0, stream>>>(AO, WoT, out);
}